// Round 7
// baseline (581.880 us; speedup 1.0000x reference)
//
#include <hip/hip_runtime.h>

typedef unsigned short u16;
typedef unsigned int u32;
typedef float f32x4 __attribute__((ext_vector_type(4)));
typedef __bf16 bf16x8 __attribute__((ext_vector_type(8)));

__device__ __forceinline__ u16 f2bf(float f) {
  u32 b = __float_as_uint(f);
  b += 0x7fffu + ((b >> 16) & 1u);
  return (u16)(b >> 16);
}

__device__ __forceinline__ void gload16(const void* g, void* l) {
  __builtin_amdgcn_global_load_lds(
      (const __attribute__((address_space(1))) void*)g,
      (__attribute__((address_space(3))) void*)l, 16, 0, 0);
}

// bijective XCD-aware block swizzle (m204 variant; works for nwg%8 != 0)
__device__ __forceinline__ int xcd_swz(int wgid, int nwg) {
  const int q = nwg >> 3, r = nwg & 7;
  const int xcd = wgid & 7, pos = wgid >> 3;
  return (xcd < r ? xcd * (q + 1) : r * (q + 1) + (xcd - r) * q) + pos;
}

// ---------------- f32 -> bf16 convert ----------------
__global__ __launch_bounds__(256)
void cvt_f32_bf16(const float4* __restrict__ in, ushort4* __restrict__ out, int n4) {
  int i = blockIdx.x * blockDim.x + threadIdx.x;
  int stride = gridDim.x * blockDim.x;
  for (; i < n4; i += stride) {
    float4 v = in[i];
    ushort4 o;
    o.x = f2bf(v.x); o.y = f2bf(v.y); o.z = f2bf(v.z); o.w = f2bf(v.w);
    out[i] = o;
  }
}

// ---------------- inverse permutation: inv[n*L + ids[n*L+l]] = l ----------------
__global__ __launch_bounds__(256)
void inv_perm(const int* __restrict__ ids, int* __restrict__ inv, int total, int L) {
  int i = blockIdx.x * 256 + threadIdx.x;
  if (i < total) {
    int n = i / L, l = i - n * L;
    inv[n * L + ids[i]] = l;
  }
}

// ---------------- 256x256 8-phase bf16 B^T GEMM ----------------
// C[m,n] = sum_k A[m,k]*B[n,k].  A [M,K], B [N,K] bf16 row-major.
// BM=BN=256, BK=64, 512 thr = 8 waves (2Mx4N). LDS 128 KiB (2 buf x (A+B)).
// Staging schedule (r6): B-LDS regions are only READ in ph0, A-regions free
// after ph2 -> iteration t stages ALL of tile t+2: B0,B1 @ph1, A0,A1 @ph3.
// ONE vmcnt(8) per iteration (outstanding 16 = tiles t+1,t+2; leave 8 ->
// tile t+1 fully landed for all waves after closing barrier). Critical lead:
// A(t+1) staged t-1 ph3 -> waited t ph3-end = 4 phases; B = 6 phases.
// Read-phases (0,2): lgkmcnt(0) between barriers -> ds_reads drained before
// any wave passes the closing barrier (stage-writes can't overtake reads).
// Swizzle: byte col ^= ((r>>1)&7)<<4 -> 2-way-free ds_read_b128; inverse
// applied on global source (both-sides-or-neither, rule #21).
// BF16OUT epilogue scatters row d -> (d/1568)*1568 + scat[d] (permuted kv).
template<bool BF16OUT>
__global__ __launch_bounds__(512, 2)
void gemm256(const u16* __restrict__ A, const u16* __restrict__ B,
             u16* __restrict__ Cb, float* __restrict__ Cf,
             const float* __restrict__ bias, const int* __restrict__ scat,
             int N, int K, int gx)
{
  __shared__ u16 LDS[2][4][8192];   // [buf][A0,A1,B0,B1][128 rows x 64 el]
  const int tid = threadIdx.x;
  const int lane = tid & 63;
  const int wid = tid >> 6;
  const int wm = wid >> 2, wn = wid & 3;       // 2 x 4 wave grid
  const int rlo = lane & 15, g4 = lane >> 4;

  const int id = xcd_swz(blockIdx.x, gridDim.x);
  const int by = id / gx, bx = id - by * gx;
  const int row0 = by * 256, col0 = bx * 256;
  const int nk = K >> 6;

  // staging geometry (per thread, per half-tile: 2 x 16B)
  const int sr = tid >> 3;                     // row 0..63 (+64 for i=1)
  const int c_phys = (tid & 7) * 16;           // linear LDS byte col in row

  auto stage = [&](int h) {
    int kt = h >> 2; if (kt > nk - 1) kt = nk - 1;   // tail clamp (writes dead/idempotent)
    const int type = h & 3;                          // 0=B0 1=B1 2=A0 3=A1
    const u16* src = (type < 2) ? B : A;
    const int rbase = ((type < 2) ? col0 : row0) + (type & 1) * 128;
    const int slot = (type < 2) ? (2 + type) : (type - 2);
    const int buf = (h >> 2) & 1;                    // parity of UNCLAMPED k-tile
    #pragma unroll
    for (int i = 0; i < 2; ++i) {
      int r = sr + i * 64;
      int c_log = c_phys ^ (((r >> 1) & 7) << 4);    // inverse swizzle on source
      const u16* g = src + (size_t)(rbase + r) * K + kt * 64 + (c_log >> 1);
      gload16(g, &LDS[buf][slot][wid * 512 + i * 4096]);  // uniform base + lane*16
    }
  };
  auto ldA = [&](int buf, int m8, int ks) -> bf16x8 {
    int row = wm * 128 + m8 * 16 + rlo;          // 0..255
    int r = row & 127;
    int col = (ks * 32 + g4 * 8) ^ (((r >> 1) & 7) << 3);   // elements
    return *(const bf16x8*)&LDS[buf][row >> 7][r * 64 + col];
  };
  auto ldB = [&](int buf, int n, int ks) -> bf16x8 {
    int row = wn * 64 + n * 16 + rlo;            // 0..255
    int r = row & 127;
    int col = (ks * 32 + g4 * 8) ^ (((r >> 1) & 7) << 3);
    return *(const bf16x8*)&LDS[buf][2 + (row >> 7)][r * 64 + col];
  };

  f32x4 acc[8][4] = {};
  bf16x8 bf[4][2], af[4][2];

  // prologue: stage tiles 0 and 1 entirely (16 loads); wait tile 0 (leave 8);
  // barrier -> ALL waves' tile-0 data landed before any read.
  #pragma unroll
  for (int h = 0; h < 8; ++h) stage(h);
  asm volatile("s_waitcnt vmcnt(8)" ::: "memory");
  __builtin_amdgcn_s_barrier();

  for (int t = 0; t < nk; ++t) {
    const int buf = t & 1;
    // ---- phase 0: reads B-all + A-lo; MFMA quadrant (0, n0..1) ----
    #pragma unroll
    for (int n = 0; n < 4; ++n)
      #pragma unroll
      for (int ks = 0; ks < 2; ++ks) bf[n][ks] = ldB(buf, n, ks);
    #pragma unroll
    for (int m = 0; m < 4; ++m)
      #pragma unroll
      for (int ks = 0; ks < 2; ++ks) af[m][ks] = ldA(buf, m, ks);
    __builtin_amdgcn_s_barrier();
    asm volatile("s_waitcnt lgkmcnt(0)" ::: "memory"); // drain ALL ds_reads
    __builtin_amdgcn_s_setprio(1);
    #pragma unroll
    for (int m = 0; m < 4; ++m)
      #pragma unroll
      for (int ks = 0; ks < 2; ++ks) {
        acc[m][0] = __builtin_amdgcn_mfma_f32_16x16x32_bf16(af[m][ks], bf[0][ks], acc[m][0], 0, 0, 0);
        acc[m][1] = __builtin_amdgcn_mfma_f32_16x16x32_bf16(af[m][ks], bf[1][ks], acc[m][1], 0, 0, 0);
      }
    __builtin_amdgcn_s_setprio(0);
    __builtin_amdgcn_s_barrier();
    // ---- phase 1: stage B0,B1 of t+2 (B regions freed by ph0); MFMA (0, n2..3) ----
    stage(4 * t + 8);
    stage(4 * t + 9);
    __builtin_amdgcn_s_barrier();
    __builtin_amdgcn_s_setprio(1);
    #pragma unroll
    for (int m = 0; m < 4; ++m)
      #pragma unroll
      for (int ks = 0; ks < 2; ++ks) {
        acc[m][2] = __builtin_amdgcn_mfma_f32_16x16x32_bf16(af[m][ks], bf[2][ks], acc[m][2], 0, 0, 0);
        acc[m][3] = __builtin_amdgcn_mfma_f32_16x16x32_bf16(af[m][ks], bf[3][ks], acc[m][3], 0, 0, 0);
      }
    __builtin_amdgcn_s_setprio(0);
    __builtin_amdgcn_s_barrier();
    // ---- phase 2: reads A-hi; MFMA quadrant (1, n0..1) ----
    #pragma unroll
    for (int m = 0; m < 4; ++m)
      #pragma unroll
      for (int ks = 0; ks < 2; ++ks) af[m][ks] = ldA(buf, 4 + m, ks);
    __builtin_amdgcn_s_barrier();
    asm volatile("s_waitcnt lgkmcnt(0)" ::: "memory");
    __builtin_amdgcn_s_setprio(1);
    #pragma unroll
    for (int m = 0; m < 4; ++m)
      #pragma unroll
      for (int ks = 0; ks < 2; ++ks) {
        acc[4 + m][0] = __builtin_amdgcn_mfma_f32_16x16x32_bf16(af[m][ks], bf[0][ks], acc[4 + m][0], 0, 0, 0);
        acc[4 + m][1] = __builtin_amdgcn_mfma_f32_16x16x32_bf16(af[m][ks], bf[1][ks], acc[4 + m][1], 0, 0, 0);
      }
    __builtin_amdgcn_s_setprio(0);
    __builtin_amdgcn_s_barrier();
    // ---- phase 3: stage A0,A1 of t+2 (A regions freed by ph2); MFMA (1, n2..3) ----
    stage(4 * t + 10);
    stage(4 * t + 11);
    __builtin_amdgcn_s_barrier();
    __builtin_amdgcn_s_setprio(1);
    #pragma unroll
    for (int m = 0; m < 4; ++m)
      #pragma unroll
      for (int ks = 0; ks < 2; ++ks) {
        acc[4 + m][2] = __builtin_amdgcn_mfma_f32_16x16x32_bf16(af[m][ks], bf[2][ks], acc[4 + m][2], 0, 0, 0);
        acc[4 + m][3] = __builtin_amdgcn_mfma_f32_16x16x32_bf16(af[m][ks], bf[3][ks], acc[4 + m][3], 0, 0, 0);
      }
    __builtin_amdgcn_s_setprio(0);
    // outstanding = tiles t+1,t+2 (16 loads); leave 8 -> tile t+1 landed.
    // barrier AFTER wait => all waves see tile t+1 complete before next reads.
    asm volatile("s_waitcnt vmcnt(8)" ::: "memory");
    __builtin_amdgcn_s_barrier();
  }

  // epilogue: C/D layout col=lane&15, row=(lane>>4)*4+v
  #pragma unroll
  for (int m = 0; m < 8; ++m) {
    #pragma unroll
    for (int n = 0; n < 4; ++n) {
      int row = row0 + wm * 128 + m * 16 + g4 * 4;
      int col = col0 + wn * 64 + n * 16 + rlo;
      #pragma unroll
      for (int v = 0; v < 4; ++v) {
        if (BF16OUT) {
          int d = row + v;                       // orig token row
          int nn = d / 1568;
          int dest = nn * 1568 + scat[d];        // shuffled position
          Cb[(size_t)dest * N + col] = f2bf(acc[m][n][v]);
        } else {
          Cf[(size_t)(row + v) * N + col] = acc[m][n][v] + bias[col];
        }
      }
    }
  }
}

// ---------------- attention: one wave per (partition, head) ----------------
// kv [50176,1536] bf16 ALREADY PERMUTED (cols 0..767 = K, 768..1535 = V).
// Q==K (reference bug). Rows for partition p are contiguous: p*49..p*49+48.
// S = Kh*Kh^T*0.125, softmax over k (cols, 49 valid), O = P*Vh -> out bf16.
__global__ __launch_bounds__(64)
void attn_part(const u16* __restrict__ kv, u16* __restrict__ out)
{
  __shared__ u16 Ksw[64 * 64];   // K tile, XOR-swizzled; reused for P
  __shared__ u16 Vt[64 * 64];    // V^T tile [d][k], XOR-swizzled
  const int lane = threadIdx.x;
  const int p = blockIdx.x / 12;
  const int h = blockIdx.x - p * 12;
  const u16* kbase = kv + (size_t)p * 49 * 1536 + h * 64;

  const int rr8 = lane >> 3, c16 = lane & 7;   // 8 rows x 8 x 16B chunks
  #pragma unroll
  for (int it = 0; it < 8; ++it) {
    int r = it * 8 + rr8;
    uint4 val = {0, 0, 0, 0};
    if (r < 49) val = *(const uint4*)(kbase + (size_t)r * 1536 + c16 * 8);
    *(uint4*)&Ksw[r * 64 + ((c16 ^ (r & 7)) * 8)] = val;
  }
  #pragma unroll
  for (int it = 0; it < 8; ++it) {
    int r = it * 8 + rr8;
    uint4 val = {0, 0, 0, 0};
    if (r < 49) val = *(const uint4*)(kbase + (size_t)r * 1536 + 768 + c16 * 8);
    const u16* vs = (const u16*)&val;
    #pragma unroll
    for (int j = 0; j < 8; ++j) {
      int d = c16 * 8 + j;
      Vt[d * 64 + (((r >> 3) ^ (d & 7)) * 8) + (r & 7)] = vs[j];
    }
  }
  __syncthreads();

  const int rlo = lane & 15, g4 = lane >> 4;
  bf16x8 af[4][2];
  #pragma unroll
  for (int m = 0; m < 4; ++m)
    #pragma unroll
    for (int g = 0; g < 2; ++g) {
      int row = m * 16 + rlo;
      af[m][g] = *(const bf16x8*)&Ksw[row * 64 + (((g * 4 + g4) ^ (row & 7)) * 8)];
    }
  f32x4 s[4][4] = {};
  #pragma unroll
  for (int m = 0; m < 4; ++m)
    #pragma unroll
    for (int nf = 0; nf < 4; ++nf)
      #pragma unroll
      for (int g = 0; g < 2; ++g)
        s[m][nf] = __builtin_amdgcn_mfma_f32_16x16x32_bf16(af[m][g], af[nf][g], s[m][nf], 0, 0, 0);

  #pragma unroll
  for (int m = 0; m < 4; ++m) {
    #pragma unroll
    for (int v = 0; v < 4; ++v) {
      float mx = -1e30f;
      #pragma unroll
      for (int nf = 0; nf < 4; ++nf) {
        float x = s[m][nf][v] * 0.125f;
        int col = nf * 16 + rlo;
        x = (col < 49) ? x : -1e30f;
        s[m][nf][v] = x;
        mx = fmaxf(mx, x);
      }
      #pragma unroll
      for (int d = 1; d < 16; d <<= 1) mx = fmaxf(mx, __shfl_xor(mx, d));
      float sum = 0.f;
      #pragma unroll
      for (int nf = 0; nf < 4; ++nf) {
        int col = nf * 16 + rlo;
        float e = (col < 49) ? __expf(s[m][nf][v] - mx) : 0.f;
        s[m][nf][v] = e;
        sum += e;
      }
      #pragma unroll
      for (int d = 1; d < 16; d <<= 1) sum += __shfl_xor(sum, d);
      float inv = 1.0f / sum;
      #pragma unroll
      for (int nf = 0; nf < 4; ++nf) s[m][nf][v] *= inv;
    }
  }

  __syncthreads();
  #pragma unroll
  for (int m = 0; m < 4; ++m)
    #pragma unroll
    for (int nf = 0; nf < 4; ++nf)
      #pragma unroll
      for (int v = 0; v < 4; ++v) {
        int R = m * 16 + g4 * 4 + v;
        int C = nf * 16 + rlo;
        Ksw[R * 64 + (((C >> 3) ^ (R & 7)) * 8) + (C & 7)] = f2bf(s[m][nf][v]);
      }
  __syncthreads();

  bf16x8 pa[4][2], vb[4][2];
  #pragma unroll
  for (int m = 0; m < 4; ++m)
    #pragma unroll
    for (int g = 0; g < 2; ++g) {
      int row = m * 16 + rlo;
      pa[m][g] = *(const bf16x8*)&Ksw[row * 64 + (((g * 4 + g4) ^ (row & 7)) * 8)];
    }
  #pragma unroll
  for (int nd = 0; nd < 4; ++nd)
    #pragma unroll
    for (int g = 0; g < 2; ++g) {
      int row = nd * 16 + rlo;
      vb[nd][g] = *(const bf16x8*)&Vt[row * 64 + (((g * 4 + g4) ^ (row & 7)) * 8)];
    }
  f32x4 o[4][4] = {};
  #pragma unroll
  for (int m = 0; m < 4; ++m)
    #pragma unroll
    for (int nd = 0; nd < 4; ++nd)
      #pragma unroll
      for (int g = 0; g < 2; ++g)
        o[m][nd] = __builtin_amdgcn_mfma_f32_16x16x32_bf16(pa[m][g], vb[nd][g], o[m][nd], 0, 0, 0);

  #pragma unroll
  for (int m = 0; m < 4; ++m)
    #pragma unroll
    for (int nd = 0; nd < 4; ++nd)
      #pragma unroll
      for (int v = 0; v < 4; ++v) {
        int q = m * 16 + g4 * 4 + v;
        if (q < 49) {
          size_t token = (size_t)p * 49 + q;
          out[token * 768 + h * 64 + nd * 16 + rlo] = f2bf(o[m][nd][v]);
        }
      }
}

// ---------------- launch ----------------
extern "C" void kernel_launch(void* const* d_in, const int* in_sizes, int n_in,
                              void* d_out, int out_size, void* d_ws, size_t ws_size,
                              hipStream_t stream) {
  const float* x      = (const float*)d_in[0];   // [32,1568,768]
  const float* w_qkv  = (const float*)d_in[1];   // [2304,768]
  const float* w_proj = (const float*)d_in[2];   // [768,768]
  const float* b_proj = (const float*)d_in[3];   // [768]
  const int*   ids    = (const int*)d_in[4];     // [32,1568]
  float* outp = (float*)d_out;

  char* ws = (char*)d_ws;
  u16* kvbuf = (u16*)ws;                                   // 154,140,672 B : kv bf16 [50176,1536] (permuted)
  u16* xbuf  = (u16*)(ws + 154140672);                     //  77,070,336 B : x bf16, later attn_out bf16
  u16* wkv   = (u16*)(ws + 154140672 + 77070336);          //   2,359,296 B : w_qkv rows 768..2303 bf16
  u16* wproj = (u16*)(ws + 154140672 + 77070336 + 2359296);//   1,179,648 B
  int* invp  = (int*)(ws + 154140672 + 77070336 + 2359296 + 1179648); // 200,704 B

  auto cgrid = [](int n4) { int g = (n4 + 255) / 256; return g > 2048 ? 2048 : g; };

  cvt_f32_bf16<<<cgrid(9633792), 256, 0, stream>>>((const float4*)x, (ushort4*)xbuf, 9633792);
  cvt_f32_bf16<<<cgrid(294912), 256, 0, stream>>>((const float4*)(w_qkv + 768 * 768), (ushort4*)wkv, 294912);
  cvt_f32_bf16<<<cgrid(147456), 256, 0, stream>>>((const float4*)w_proj, (ushort4*)wproj, 147456);
  inv_perm<<<196, 256, 0, stream>>>(ids, invp, 50176, 1568);

  // kv = x @ w_kv^T scattered to shuffled rows : M=50176, N=1536, K=768
  gemm256<true><<<dim3(6 * 196), 512, 0, stream>>>(xbuf, wkv, kvbuf, nullptr, nullptr, invp, 1536, 768, 6);

  // attention (1024 partitions x 12 heads), contiguous rows, writes attn_out into xbuf
  attn_part<<<12288, 64, 0, stream>>>(kvbuf, xbuf);

  // out = attn_out @ w_proj^T + b : M=50176, N=768, K=768
  gemm256<false><<<dim3(3 * 196), 512, 0, stream>>>(xbuf, wproj, nullptr, outp, b_proj, nullptr, 768, 768, 3);
}

// Round 8
// 568.426 us; speedup vs baseline: 1.0237x; 1.0237x over previous
//
#include <hip/hip_runtime.h>

typedef unsigned short u16;
typedef unsigned int u32;
typedef float f32x4 __attribute__((ext_vector_type(4)));
typedef __bf16 bf16x8 __attribute__((ext_vector_type(8)));

__device__ __forceinline__ u16 f2bf(float f) {
  u32 b = __float_as_uint(f);
  b += 0x7fffu + ((b >> 16) & 1u);
  return (u16)(b >> 16);
}

__device__ __forceinline__ void gload16(const void* g, void* l) {
  __builtin_amdgcn_global_load_lds(
      (const __attribute__((address_space(1))) void*)g,
      (__attribute__((address_space(3))) void*)l, 16, 0, 0);
}

// bijective XCD-aware block swizzle (m204 variant; works for nwg%8 != 0)
__device__ __forceinline__ int xcd_swz(int wgid, int nwg) {
  const int q = nwg >> 3, r = nwg & 7;
  const int xcd = wgid & 7, pos = wgid >> 3;
  return (xcd < r ? xcd * (q + 1) : r * (q + 1) + (xcd - r) * q) + pos;
}

// ---------------- f32 -> bf16 convert ----------------
__global__ __launch_bounds__(256)
void cvt_f32_bf16(const float4* __restrict__ in, ushort4* __restrict__ out, int n4) {
  int i = blockIdx.x * blockDim.x + threadIdx.x;
  int stride = gridDim.x * blockDim.x;
  for (; i < n4; i += stride) {
    float4 v = in[i];
    ushort4 o;
    o.x = f2bf(v.x); o.y = f2bf(v.y); o.z = f2bf(v.z); o.w = f2bf(v.w);
    out[i] = o;
  }
}

// ---------------- inverse permutation: inv[n*L + ids[n*L+l]] = l ----------------
__global__ __launch_bounds__(256)
void inv_perm(const int* __restrict__ ids, int* __restrict__ inv, int total, int L) {
  int i = blockIdx.x * 256 + threadIdx.x;
  if (i < total) {
    int n = i / L, l = i - n * L;
    inv[n * L + ids[i]] = l;
  }
}

// ---------------- 256x256 8-phase bf16 B^T GEMM ----------------
// C[m,n] = sum_k A[m,k]*B[n,k].  A [M,K], B [N,K] bf16 row-major.
// BM=BN=256, BK=64, 512 thr = 8 waves (2Mx4N). LDS 128 KiB (2 buf x (A+B)).
// Staging = r5 measured-best (m201 pattern): ONE half-tile per phase --
//   ph0: (t+1).A1, ph1: (t+2).B0, ph2: (t+2).B1, ph3: (t+2).A0
// prologue stages h=0..6 (7 halves), vmcnt(6) -> tile0's 8 loads landed.
// per-iter: single vmcnt(6) at ph3-end BEFORE closing barrier (14 loads
// outstanding, leave 6 -> tile t+1's 8 landed; barrier publishes x-wave).
// Read-phases (0,2): lgkmcnt(0) between barriers -> ds_reads drained before
// any wave passes the closing barrier (stage-writes can't overtake reads).
// Swizzle: byte col ^= ((r>>1)&7)<<4 -> 2-way-free ds_read_b128; inverse
// applied on global source (both-sides-or-neither, rule #21).
// BF16OUT epilogue scatters row d -> (d/1568)*1568 + scat[d] (permuted kv).
template<bool BF16OUT>
__global__ __launch_bounds__(512, 2)
void gemm256(const u16* __restrict__ A, const u16* __restrict__ B,
             u16* __restrict__ Cb, float* __restrict__ Cf,
             const float* __restrict__ bias, const int* __restrict__ scat,
             int N, int K, int gx)
{
  __shared__ u16 LDS[2][4][8192];   // [buf][A0,A1,B0,B1][128 rows x 64 el]
  const int tid = threadIdx.x;
  const int lane = tid & 63;
  const int wid = tid >> 6;
  const int wm = wid >> 2, wn = wid & 3;       // 2 x 4 wave grid
  const int rlo = lane & 15, g4 = lane >> 4;

  const int id = xcd_swz(blockIdx.x, gridDim.x);
  const int by = id / gx, bx = id - by * gx;
  const int row0 = by * 256, col0 = bx * 256;
  const int nk = K >> 6;

  // staging geometry (per thread, per half-tile: 2 x 16B)
  const int sr = tid >> 3;                     // row 0..63 (+64 for i=1)
  const int c_phys = (tid & 7) * 16;           // linear LDS byte col in row

  auto stage = [&](int h) {
    int kt = h >> 2; if (kt > nk - 1) kt = nk - 1;   // tail clamp (writes dead/idempotent)
    const int type = h & 3;                          // 0=B0 1=B1 2=A0 3=A1
    const u16* src = (type < 2) ? B : A;
    const int rbase = ((type < 2) ? col0 : row0) + (type & 1) * 128;
    const int slot = (type < 2) ? (2 + type) : (type - 2);
    const int buf = (h >> 2) & 1;                    // parity of UNCLAMPED k-tile
    #pragma unroll
    for (int i = 0; i < 2; ++i) {
      int r = sr + i * 64;
      int c_log = c_phys ^ (((r >> 1) & 7) << 4);    // inverse swizzle on source
      const u16* g = src + (size_t)(rbase + r) * K + kt * 64 + (c_log >> 1);
      gload16(g, &LDS[buf][slot][wid * 512 + i * 4096]);  // uniform base + lane*16
    }
  };
  auto ldA = [&](int buf, int m8, int ks) -> bf16x8 {
    int row = wm * 128 + m8 * 16 + rlo;          // 0..255
    int r = row & 127;
    int col = (ks * 32 + g4 * 8) ^ (((r >> 1) & 7) << 3);   // elements
    return *(const bf16x8*)&LDS[buf][row >> 7][r * 64 + col];
  };
  auto ldB = [&](int buf, int n, int ks) -> bf16x8 {
    int row = wn * 64 + n * 16 + rlo;            // 0..255
    int r = row & 127;
    int col = (ks * 32 + g4 * 8) ^ (((r >> 1) & 7) << 3);
    return *(const bf16x8*)&LDS[buf][2 + (row >> 7)][r * 64 + col];
  };

  f32x4 acc[8][4] = {};
  bf16x8 bf[4][2], af[4][2];

  // prologue: stage 7 half-tiles (K0 complete + K1 B0,B1,A0);
  // vmcnt(6): 14 loads out, leave 6 -> tile0's 8 landed; barrier -> all waves.
  #pragma unroll
  for (int h = 0; h < 7; ++h) stage(h);
  asm volatile("s_waitcnt vmcnt(6)" ::: "memory");
  __builtin_amdgcn_s_barrier();

  for (int t = 0; t < nk; ++t) {
    const int buf = t & 1;
    // ---- phase 0: reads B-all + A-lo; stage (t+1).A1; MFMA quadrant (0, n0..1) ----
    #pragma unroll
    for (int n = 0; n < 4; ++n)
      #pragma unroll
      for (int ks = 0; ks < 2; ++ks) bf[n][ks] = ldB(buf, n, ks);
    #pragma unroll
    for (int m = 0; m < 4; ++m)
      #pragma unroll
      for (int ks = 0; ks < 2; ++ks) af[m][ks] = ldA(buf, m, ks);
    stage(4 * t + 7);                                  // (t+1).A1 -> other buf
    __builtin_amdgcn_s_barrier();
    asm volatile("s_waitcnt lgkmcnt(0)" ::: "memory"); // drain ALL ds_reads
    __builtin_amdgcn_s_setprio(1);
    #pragma unroll
    for (int m = 0; m < 4; ++m)
      #pragma unroll
      for (int ks = 0; ks < 2; ++ks) {
        acc[m][0] = __builtin_amdgcn_mfma_f32_16x16x32_bf16(af[m][ks], bf[0][ks], acc[m][0], 0, 0, 0);
        acc[m][1] = __builtin_amdgcn_mfma_f32_16x16x32_bf16(af[m][ks], bf[1][ks], acc[m][1], 0, 0, 0);
      }
    __builtin_amdgcn_s_setprio(0);
    __builtin_amdgcn_s_barrier();
    // ---- phase 1: stage (t+2).B0 (B0 freed by ph0 drain); MFMA (0, n2..3) ----
    stage(4 * t + 8);
    __builtin_amdgcn_s_barrier();
    __builtin_amdgcn_s_setprio(1);
    #pragma unroll
    for (int m = 0; m < 4; ++m)
      #pragma unroll
      for (int ks = 0; ks < 2; ++ks) {
        acc[m][2] = __builtin_amdgcn_mfma_f32_16x16x32_bf16(af[m][ks], bf[2][ks], acc[m][2], 0, 0, 0);
        acc[m][3] = __builtin_amdgcn_mfma_f32_16x16x32_bf16(af[m][ks], bf[3][ks], acc[m][3], 0, 0, 0);
      }
    __builtin_amdgcn_s_setprio(0);
    __builtin_amdgcn_s_barrier();
    // ---- phase 2: reads A-hi; stage (t+2).B1; MFMA quadrant (1, n0..1) ----
    #pragma unroll
    for (int m = 0; m < 4; ++m)
      #pragma unroll
      for (int ks = 0; ks < 2; ++ks) af[m][ks] = ldA(buf, 4 + m, ks);
    stage(4 * t + 9);
    __builtin_amdgcn_s_barrier();
    asm volatile("s_waitcnt lgkmcnt(0)" ::: "memory");
    __builtin_amdgcn_s_setprio(1);
    #pragma unroll
    for (int m = 0; m < 4; ++m)
      #pragma unroll
      for (int ks = 0; ks < 2; ++ks) {
        acc[4 + m][0] = __builtin_amdgcn_mfma_f32_16x16x32_bf16(af[m][ks], bf[0][ks], acc[4 + m][0], 0, 0, 0);
        acc[4 + m][1] = __builtin_amdgcn_mfma_f32_16x16x32_bf16(af[m][ks], bf[1][ks], acc[4 + m][1], 0, 0, 0);
      }
    __builtin_amdgcn_s_setprio(0);
    __builtin_amdgcn_s_barrier();
    // ---- phase 3: stage (t+2).A0 (A0 freed by ph2 drain); MFMA (1, n2..3); vmcnt(6) ----
    stage(4 * t + 10);
    __builtin_amdgcn_s_barrier();
    __builtin_amdgcn_s_setprio(1);
    #pragma unroll
    for (int m = 0; m < 4; ++m)
      #pragma unroll
      for (int ks = 0; ks < 2; ++ks) {
        acc[4 + m][2] = __builtin_amdgcn_mfma_f32_16x16x32_bf16(af[m][ks], bf[2][ks], acc[4 + m][2], 0, 0, 0);
        acc[4 + m][3] = __builtin_amdgcn_mfma_f32_16x16x32_bf16(af[m][ks], bf[3][ks], acc[4 + m][3], 0, 0, 0);
      }
    __builtin_amdgcn_s_setprio(0);
    // outstanding = h 4t+7..4t+10 staged this iter + carryover = 14 loads;
    // leave 6 -> h<=4t+7 landed => tile t+1 complete. barrier publishes.
    asm volatile("s_waitcnt vmcnt(6)" ::: "memory");
    __builtin_amdgcn_s_barrier();
  }

  // epilogue: C/D layout col=lane&15, row=(lane>>4)*4+v
  #pragma unroll
  for (int m = 0; m < 8; ++m) {
    #pragma unroll
    for (int n = 0; n < 4; ++n) {
      int row = row0 + wm * 128 + m * 16 + g4 * 4;
      int col = col0 + wn * 64 + n * 16 + rlo;
      #pragma unroll
      for (int v = 0; v < 4; ++v) {
        if (BF16OUT) {
          int d = row + v;                       // orig token row
          int nn = d / 1568;
          int dest = nn * 1568 + scat[d];        // shuffled position
          Cb[(size_t)dest * N + col] = f2bf(acc[m][n][v]);
        } else {
          Cf[(size_t)(row + v) * N + col] = acc[m][n][v] + bias[col];
        }
      }
    }
  }
}

// ---------------- attention: one wave per (partition, head) ----------------
// kv [50176,1536] bf16 ALREADY PERMUTED (cols 0..767 = K, 768..1535 = V).
// Q==K (reference bug). Rows for partition p are contiguous: p*49..p*49+48.
// S = Kh*Kh^T*0.125, softmax over k (cols, 49 valid), O = P*Vh -> out bf16.
__global__ __launch_bounds__(64)
void attn_part(const u16* __restrict__ kv, u16* __restrict__ out)
{
  __shared__ u16 Ksw[64 * 64];   // K tile, XOR-swizzled; reused for P
  __shared__ u16 Vt[64 * 64];    // V^T tile [d][k], XOR-swizzled
  const int lane = threadIdx.x;
  const int p = blockIdx.x / 12;
  const int h = blockIdx.x - p * 12;
  const u16* kbase = kv + (size_t)p * 49 * 1536 + h * 64;

  const int rr8 = lane >> 3, c16 = lane & 7;   // 8 rows x 8 x 16B chunks
  #pragma unroll
  for (int it = 0; it < 8; ++it) {
    int r = it * 8 + rr8;
    uint4 val = {0, 0, 0, 0};
    if (r < 49) val = *(const uint4*)(kbase + (size_t)r * 1536 + c16 * 8);
    *(uint4*)&Ksw[r * 64 + ((c16 ^ (r & 7)) * 8)] = val;
  }
  #pragma unroll
  for (int it = 0; it < 8; ++it) {
    int r = it * 8 + rr8;
    uint4 val = {0, 0, 0, 0};
    if (r < 49) val = *(const uint4*)(kbase + (size_t)r * 1536 + 768 + c16 * 8);
    const u16* vs = (const u16*)&val;
    #pragma unroll
    for (int j = 0; j < 8; ++j) {
      int d = c16 * 8 + j;
      Vt[d * 64 + (((r >> 3) ^ (d & 7)) * 8) + (r & 7)] = vs[j];
    }
  }
  __syncthreads();

  const int rlo = lane & 15, g4 = lane >> 4;
  bf16x8 af[4][2];
  #pragma unroll
  for (int m = 0; m < 4; ++m)
    #pragma unroll
    for (int g = 0; g < 2; ++g) {
      int row = m * 16 + rlo;
      af[m][g] = *(const bf16x8*)&Ksw[row * 64 + (((g * 4 + g4) ^ (row & 7)) * 8)];
    }
  f32x4 s[4][4] = {};
  #pragma unroll
  for (int m = 0; m < 4; ++m)
    #pragma unroll
    for (int nf = 0; nf < 4; ++nf)
      #pragma unroll
      for (int g = 0; g < 2; ++g)
        s[m][nf] = __builtin_amdgcn_mfma_f32_16x16x32_bf16(af[m][g], af[nf][g], s[m][nf], 0, 0, 0);

  #pragma unroll
  for (int m = 0; m < 4; ++m) {
    #pragma unroll
    for (int v = 0; v < 4; ++v) {
      float mx = -1e30f;
      #pragma unroll
      for (int nf = 0; nf < 4; ++nf) {
        float x = s[m][nf][v] * 0.125f;
        int col = nf * 16 + rlo;
        x = (col < 49) ? x : -1e30f;
        s[m][nf][v] = x;
        mx = fmaxf(mx, x);
      }
      #pragma unroll
      for (int d = 1; d < 16; d <<= 1) mx = fmaxf(mx, __shfl_xor(mx, d));
      float sum = 0.f;
      #pragma unroll
      for (int nf = 0; nf < 4; ++nf) {
        int col = nf * 16 + rlo;
        float e = (col < 49) ? __expf(s[m][nf][v] - mx) : 0.f;
        s[m][nf][v] = e;
        sum += e;
      }
      #pragma unroll
      for (int d = 1; d < 16; d <<= 1) sum += __shfl_xor(sum, d);
      float inv = 1.0f / sum;
      #pragma unroll
      for (int nf = 0; nf < 4; ++nf) s[m][nf][v] *= inv;
    }
  }

  __syncthreads();
  #pragma unroll
  for (int m = 0; m < 4; ++m)
    #pragma unroll
    for (int nf = 0; nf < 4; ++nf)
      #pragma unroll
      for (int v = 0; v < 4; ++v) {
        int R = m * 16 + g4 * 4 + v;
        int C = nf * 16 + rlo;
        Ksw[R * 64 + (((C >> 3) ^ (R & 7)) * 8) + (C & 7)] = f2bf(s[m][nf][v]);
      }
  __syncthreads();

  bf16x8 pa[4][2], vb[4][2];
  #pragma unroll
  for (int m = 0; m < 4; ++m)
    #pragma unroll
    for (int g = 0; g < 2; ++g) {
      int row = m * 16 + rlo;
      pa[m][g] = *(const bf16x8*)&Ksw[row * 64 + (((g * 4 + g4) ^ (row & 7)) * 8)];
    }
  #pragma unroll
  for (int nd = 0; nd < 4; ++nd)
    #pragma unroll
    for (int g = 0; g < 2; ++g) {
      int row = nd * 16 + rlo;
      vb[nd][g] = *(const bf16x8*)&Vt[row * 64 + (((g * 4 + g4) ^ (row & 7)) * 8)];
    }
  f32x4 o[4][4] = {};
  #pragma unroll
  for (int m = 0; m < 4; ++m)
    #pragma unroll
    for (int nd = 0; nd < 4; ++nd)
      #pragma unroll
      for (int g = 0; g < 2; ++g)
        o[m][nd] = __builtin_amdgcn_mfma_f32_16x16x32_bf16(pa[m][g], vb[nd][g], o[m][nd], 0, 0, 0);

  #pragma unroll
  for (int m = 0; m < 4; ++m)
    #pragma unroll
    for (int nd = 0; nd < 4; ++nd)
      #pragma unroll
      for (int v = 0; v < 4; ++v) {
        int q = m * 16 + g4 * 4 + v;
        if (q < 49) {
          size_t token = (size_t)p * 49 + q;
          out[token * 768 + h * 64 + nd * 16 + rlo] = f2bf(o[m][nd][v]);
        }
      }
}

// ---------------- launch ----------------
extern "C" void kernel_launch(void* const* d_in, const int* in_sizes, int n_in,
                              void* d_out, int out_size, void* d_ws, size_t ws_size,
                              hipStream_t stream) {
  const float* x      = (const float*)d_in[0];   // [32,1568,768]
  const float* w_qkv  = (const float*)d_in[1];   // [2304,768]
  const float* w_proj = (const float*)d_in[2];   // [768,768]
  const float* b_proj = (const float*)d_in[3];   // [768]
  const int*   ids    = (const int*)d_in[4];     // [32,1568]
  float* outp = (float*)d_out;

  char* ws = (char*)d_ws;
  u16* kvbuf = (u16*)ws;                                   // 154,140,672 B : kv bf16 [50176,1536] (permuted)
  u16* xbuf  = (u16*)(ws + 154140672);                     //  77,070,336 B : x bf16, later attn_out bf16
  u16* wkv   = (u16*)(ws + 154140672 + 77070336);          //   2,359,296 B : w_qkv rows 768..2303 bf16
  u16* wproj = (u16*)(ws + 154140672 + 77070336 + 2359296);//   1,179,648 B
  int* invp  = (int*)(ws + 154140672 + 77070336 + 2359296 + 1179648); // 200,704 B

  auto cgrid = [](int n4) { int g = (n4 + 255) / 256; return g > 2048 ? 2048 : g; };

  cvt_f32_bf16<<<cgrid(9633792), 256, 0, stream>>>((const float4*)x, (ushort4*)xbuf, 9633792);
  cvt_f32_bf16<<<cgrid(294912), 256, 0, stream>>>((const float4*)(w_qkv + 768 * 768), (ushort4*)wkv, 294912);
  cvt_f32_bf16<<<cgrid(147456), 256, 0, stream>>>((const float4*)w_proj, (ushort4*)wproj, 147456);
  inv_perm<<<196, 256, 0, stream>>>(ids, invp, 50176, 1568);

  // kv = x @ w_kv^T scattered to shuffled rows : M=50176, N=1536, K=768
  gemm256<true><<<dim3(6 * 196), 512, 0, stream>>>(xbuf, wkv, kvbuf, nullptr, nullptr, invp, 1536, 768, 6);

  // attention (1024 partitions x 12 heads), contiguous rows, writes attn_out into xbuf
  attn_part<<<12288, 64, 0, stream>>>(kvbuf, xbuf);

  // out = attn_out @ w_proj^T + b : M=50176, N=768, K=768
  gemm256<false><<<dim3(3 * 196), 512, 0, stream>>>(xbuf, wproj, nullptr, outp, b_proj, nullptr, 768, 768, 3);
}